// Round 1
// baseline (1128.499 us; speedup 1.0000x reference)
//
#include <hip/hip_runtime.h>

#define N_TOK 8192
#define DIM   1024
#define FFN   4096
#define NEXP  8
#define TOPK  2
#define NENT  (N_TOK * TOPK)   // 16384

using short8  = __attribute__((ext_vector_type(8))) short;
using floatx4 = __attribute__((ext_vector_type(4))) float;

__device__ __forceinline__ unsigned short f2bf(float f) {
    union { float f; unsigned u; } v; v.f = f;
    unsigned r = v.u + 0x7fffu + ((v.u >> 16) & 1u);   // round-to-nearest-even
    return (unsigned short)(r >> 16);
}

#define GLOAD_LDS16(gptr, lptr) __builtin_amdgcn_global_load_lds( \
    (__attribute__((address_space(1))) void*)(void*)(gptr),       \
    (__attribute__((address_space(3))) void*)(lptr), 16, 0, 0)

// ---------------- conversion kernels ----------------

__global__ __launch_bounds__(256) void cvt_x_kernel(const float4* __restrict__ in,
                                                    ushort4* __restrict__ out) {
    int i = blockIdx.x * 256 + threadIdx.x;   // grid sized exactly
    float4 v = in[i];
    ushort4 o;
    o.x = f2bf(v.x); o.y = f2bf(v.y); o.z = f2bf(v.z); o.w = f2bf(v.w);
    out[i] = o;
}

// in: [E][R][C] f32  ->  out: [E][C][R] bf16
__global__ __launch_bounds__(256) void transpose_cvt(const float* __restrict__ in,
                                                     unsigned short* __restrict__ out,
                                                     int R, int C) {
    __shared__ float tile[32][33];
    int e  = blockIdx.z;
    int c0 = blockIdx.x * 32;
    int r0 = blockIdx.y * 32;
    const float* inp = in + (size_t)e * R * C;
    unsigned short* outp = out + (size_t)e * R * C;
    int tx = threadIdx.x, ty = threadIdx.y;
#pragma unroll
    for (int i = 0; i < 4; i++) {
        int r = ty + i * 8;
        tile[r][tx] = inp[(size_t)(r0 + r) * C + c0 + tx];
    }
    __syncthreads();
#pragma unroll
    for (int i = 0; i < 4; i++) {
        int c = ty + i * 8;
        outp[(size_t)(c0 + c) * R + r0 + tx] = f2bf(tile[tx][c]);
    }
}

// ---------------- gating / routing ----------------

__global__ __launch_bounds__(256) void gating_kernel(const float* __restrict__ x,
                                                     const float* __restrict__ wg,
                                                     int* __restrict__ topk_e,
                                                     float* __restrict__ topk_w,
                                                     int* __restrict__ counts) {
    int wave = threadIdx.x >> 6, lane = threadIdx.x & 63;
    int t = blockIdx.x * 4 + wave;
    const float* xr = x + (size_t)t * DIM;
    float acc[NEXP];
#pragma unroll
    for (int e = 0; e < NEXP; e++) acc[e] = 0.f;
    for (int it = 0; it < DIM / 64; it++) {
        int d = it * 64 + lane;
        float xv = xr[d];
        const float4* wr = (const float4*)(wg + d * NEXP);
        float4 w0 = wr[0], w1 = wr[1];
        acc[0] += xv * w0.x; acc[1] += xv * w0.y; acc[2] += xv * w0.z; acc[3] += xv * w0.w;
        acc[4] += xv * w1.x; acc[5] += xv * w1.y; acc[6] += xv * w1.z; acc[7] += xv * w1.w;
    }
#pragma unroll
    for (int e = 0; e < NEXP; e++) {
#pragma unroll
        for (int off = 32; off > 0; off >>= 1) acc[e] += __shfl_xor(acc[e], off);
    }
    if (lane == 0) {
        int e1 = 0; float l1 = acc[0];
        for (int e = 1; e < NEXP; e++) if (acc[e] > l1) { l1 = acc[e]; e1 = e; }
        int e2 = -1; float l2 = -3.4e38f;
        for (int e = 0; e < NEXP; e++) if (e != e1 && acc[e] > l2) { l2 = acc[e]; e2 = e; }
        float w1v = 1.f / (1.f + expf(l2 - l1));   // softmax top-2 renormalized
        topk_e[t * 2]     = e1;  topk_e[t * 2 + 1] = e2;
        topk_w[t * 2]     = w1v; topk_w[t * 2 + 1] = 1.f - w1v;
        atomicAdd(&counts[e1], 1);
        atomicAdd(&counts[e2], 1);
    }
}

__global__ void prefix_kernel(const int* __restrict__ counts, int* __restrict__ offs) {
    if (threadIdx.x == 0) {
        int s = 0;
        for (int e = 0; e < NEXP; e++) { offs[e] = s; s += counts[e]; }
        offs[NEXP] = s;
    }
}

__global__ __launch_bounds__(256) void scatter_kernel(const int* __restrict__ topk_e,
                                                      const float* __restrict__ topk_w,
                                                      const int* __restrict__ offs,
                                                      int* __restrict__ cursors,
                                                      int* __restrict__ entry_token,
                                                      float* __restrict__ entry_wgt) {
    int t = blockIdx.x * 256 + threadIdx.x;   // grid exact
#pragma unroll
    for (int k = 0; k < TOPK; k++) {
        int e = topk_e[t * 2 + k];
        int pos = offs[e] + atomicAdd(&cursors[e], 1);
        entry_token[pos] = t;
        entry_wgt[pos]  = topk_w[t * 2 + k];
    }
}

// ---------------- GEMM1: h = relu(x[tok] @ W1_e + b1_e) ----------------
// A: gathered x_bf16 rows (M x 1024), B^T: w1t [E][FFN][DIM], tile 128x128, BK=32

__global__ __launch_bounds__(256) void gemm1_kernel(
    const unsigned short* __restrict__ xb,    // [N_TOK][DIM] bf16
    const unsigned short* __restrict__ w1t,   // [E][FFN][DIM] bf16
    const float* __restrict__ b1,             // [E][FFN]
    const int* __restrict__ offs,
    const int* __restrict__ entry_token,
    unsigned short* __restrict__ h)           // [NENT+128][FFN] bf16
{
    int e    = blockIdx.z;
    int base = offs[e];
    int cnt  = offs[e + 1] - base;
    int m0   = blockIdx.y * 128;
    if (m0 >= cnt) return;
    int f0   = blockIdx.x * 128;

    __shared__ unsigned short As[128 * 32];   // [row][k] 64B rows
    __shared__ unsigned short Bs[128 * 32];
    __shared__ int toks[128];

    int tid = threadIdx.x;
    if (tid < 128) {
        int r = m0 + tid;
        toks[tid] = entry_token[base + (r < cnt ? r : 0)];
    }
    __syncthreads();

    int wave = tid >> 6, lane = tid & 63;
    int wm = (wave >> 1) * 64, wn = (wave & 1) * 64;

    // staging: wave w stages 1KB chunks {2w,2w+1} of A and of B (16 rows each)
    int rA   = wave * 32 + (lane >> 2);
    int colg = (lane & 3) * 8;
    const unsigned short* aG0 = xb + (size_t)toks[rA] * DIM + colg;
    const unsigned short* aG1 = xb + (size_t)toks[rA + 16] * DIM + colg;
    const unsigned short* bG0 = w1t + ((size_t)e * FFN + f0 + rA) * DIM + colg;
    const unsigned short* bG1 = bG0 + (size_t)16 * DIM;
    unsigned short* ldsA0 = &As[wave * 1024];
    unsigned short* ldsA1 = &As[wave * 1024 + 512];
    unsigned short* ldsB0 = &Bs[wave * 1024];
    unsigned short* ldsB1 = &Bs[wave * 1024 + 512];

    floatx4 acc[4][4];
#pragma unroll
    for (int i = 0; i < 4; i++)
#pragma unroll
        for (int j = 0; j < 4; j++) acc[i][j] = (floatx4)0.f;

    int quad = lane >> 4, rm = lane & 15;
    int aoff = (wm + rm) * 32 + quad * 8;
    int boff = (wn + rm) * 32 + quad * 8;

    for (int kk = 0; kk < DIM / 32; kk++) {
        GLOAD_LDS16(aG0, ldsA0);
        GLOAD_LDS16(aG1, ldsA1);
        GLOAD_LDS16(bG0, ldsB0);
        GLOAD_LDS16(bG1, ldsB1);
        aG0 += 32; aG1 += 32; bG0 += 32; bG1 += 32;
        __syncthreads();
        short8 af[4], bfr[4];
#pragma unroll
        for (int mi = 0; mi < 4; mi++) af[mi] = *(const short8*)&As[aoff + mi * 512];
#pragma unroll
        for (int ni = 0; ni < 4; ni++) bfr[ni] = *(const short8*)&Bs[boff + ni * 512];
#pragma unroll
        for (int mi = 0; mi < 4; mi++)
#pragma unroll
            for (int ni = 0; ni < 4; ni++)
                acc[mi][ni] = __builtin_amdgcn_mfma_f32_16x16x32_bf16(af[mi], bfr[ni], acc[mi][ni], 0, 0, 0);
        __syncthreads();
    }

    // epilogue: D layout col = lane&15, row = quad*4 + r
#pragma unroll
    for (int mi = 0; mi < 4; mi++) {
        int mbase = wm + mi * 16 + quad * 4;
#pragma unroll
        for (int ni = 0; ni < 4; ni++) {
            int f = f0 + wn + ni * 16 + rm;
            float bias = b1[e * FFN + f];
            floatx4 v = acc[mi][ni];
#pragma unroll
            for (int r = 0; r < 4; r++) {
                int row = m0 + mbase + r;
                if (row < cnt) {
                    float t = v[r] + bias;
                    t = t > 0.f ? t : 0.f;
                    h[(size_t)(base + row) * FFN + f] = f2bf(t);
                }
            }
        }
    }
}

// ---------------- GEMM2: y[tok] += w * (h @ W2_e + b2_e) ----------------

__global__ __launch_bounds__(256) void gemm2_kernel(
    const unsigned short* __restrict__ h,     // [NENT+128][FFN]
    const unsigned short* __restrict__ w2t,   // [E][DIM][FFN]
    const float* __restrict__ b2,             // [E][DIM]
    const int* __restrict__ offs,
    const int* __restrict__ entry_token,
    const float* __restrict__ entry_wgt,
    float* __restrict__ y)                    // [N_TOK][DIM]
{
    int e    = blockIdx.z;
    int base = offs[e];
    int cnt  = offs[e + 1] - base;
    int m0   = blockIdx.y * 128;
    if (m0 >= cnt) return;
    int n0   = blockIdx.x * 128;

    __shared__ unsigned short As[128 * 32];
    __shared__ unsigned short Bs[128 * 32];

    int tid = threadIdx.x;
    int wave = tid >> 6, lane = tid & 63;
    int wm = (wave >> 1) * 64, wn = (wave & 1) * 64;

    int rA   = wave * 32 + (lane >> 2);
    int colg = (lane & 3) * 8;
    const unsigned short* aG0 = h + (size_t)(base + m0 + rA) * FFN + colg;
    const unsigned short* aG1 = aG0 + (size_t)16 * FFN;
    const unsigned short* bG0 = w2t + ((size_t)e * DIM + n0 + rA) * FFN + colg;
    const unsigned short* bG1 = bG0 + (size_t)16 * FFN;
    unsigned short* ldsA0 = &As[wave * 1024];
    unsigned short* ldsA1 = &As[wave * 1024 + 512];
    unsigned short* ldsB0 = &Bs[wave * 1024];
    unsigned short* ldsB1 = &Bs[wave * 1024 + 512];

    floatx4 acc[4][4];
#pragma unroll
    for (int i = 0; i < 4; i++)
#pragma unroll
        for (int j = 0; j < 4; j++) acc[i][j] = (floatx4)0.f;

    int quad = lane >> 4, rm = lane & 15;
    int aoff = (wm + rm) * 32 + quad * 8;
    int boff = (wn + rm) * 32 + quad * 8;

    for (int kk = 0; kk < FFN / 32; kk++) {
        GLOAD_LDS16(aG0, ldsA0);
        GLOAD_LDS16(aG1, ldsA1);
        GLOAD_LDS16(bG0, ldsB0);
        GLOAD_LDS16(bG1, ldsB1);
        aG0 += 32; aG1 += 32; bG0 += 32; bG1 += 32;
        __syncthreads();
        short8 af[4], bfr[4];
#pragma unroll
        for (int mi = 0; mi < 4; mi++) af[mi] = *(const short8*)&As[aoff + mi * 512];
#pragma unroll
        for (int ni = 0; ni < 4; ni++) bfr[ni] = *(const short8*)&Bs[boff + ni * 512];
#pragma unroll
        for (int mi = 0; mi < 4; mi++)
#pragma unroll
            for (int ni = 0; ni < 4; ni++)
                acc[mi][ni] = __builtin_amdgcn_mfma_f32_16x16x32_bf16(af[mi], bfr[ni], acc[mi][ni], 0, 0, 0);
        __syncthreads();
    }

#pragma unroll
    for (int mi = 0; mi < 4; mi++) {
        int mbase = wm + mi * 16 + quad * 4;
#pragma unroll
        for (int ni = 0; ni < 4; ni++) {
            int n = n0 + wn + ni * 16 + rm;
            float bias = b2[e * DIM + n];
            floatx4 v = acc[mi][ni];
#pragma unroll
            for (int r = 0; r < 4; r++) {
                int row = m0 + mbase + r;
                if (row < cnt) {
                    int   tok = entry_token[base + row];
                    float w   = entry_wgt[base + row];
                    atomicAdd(&y[(size_t)tok * DIM + n], (v[r] + bias) * w);
                }
            }
        }
    }
}

// ---------------- launch ----------------

extern "C" void kernel_launch(void* const* d_in, const int* in_sizes, int n_in,
                              void* d_out, int out_size, void* d_ws, size_t ws_size,
                              hipStream_t stream) {
    const float* x  = (const float*)d_in[0];
    const float* Wg = (const float*)d_in[1];
    const float* W1 = (const float*)d_in[2];
    const float* b1 = (const float*)d_in[3];
    const float* W2 = (const float*)d_in[4];
    const float* b2 = (const float*)d_in[5];
    float* y = (float*)d_out;

    char* p = (char*)d_ws;
    unsigned short* xb  = (unsigned short*)p; p += (size_t)N_TOK * DIM * 2;          // 16 MB
    unsigned short* w1t = (unsigned short*)p; p += (size_t)NEXP * DIM * FFN * 2;     // 64 MB
    unsigned short* w2t = (unsigned short*)p; p += (size_t)NEXP * DIM * FFN * 2;     // 64 MB
    unsigned short* h   = (unsigned short*)p; p += (size_t)(NENT + 128) * FFN * 2;   // 129 MB
    int*   topk_e      = (int*)p;   p += (size_t)N_TOK * TOPK * 4;
    float* topk_w      = (float*)p; p += (size_t)N_TOK * TOPK * 4;
    int*   entry_token = (int*)p;   p += (size_t)NENT * 4;
    float* entry_wgt   = (float*)p; p += (size_t)NENT * 4;
    int*   counts      = (int*)p;   p += NEXP * 4;
    int*   cursors     = (int*)p;   p += NEXP * 4;
    int*   offs        = (int*)p;   p += (NEXP + 1) * 4;

    hipMemsetAsync(d_out, 0, (size_t)out_size * 4, stream);
    hipMemsetAsync(counts, 0, NEXP * 4 * 2, stream);   // counts + cursors (adjacent)

    cvt_x_kernel<<<(N_TOK * DIM) / (256 * 4), 256, 0, stream>>>((const float4*)x, (ushort4*)xb);
    transpose_cvt<<<dim3(FFN / 32, DIM / 32, NEXP), dim3(32, 8), 0, stream>>>(W1, w1t, DIM, FFN);
    transpose_cvt<<<dim3(DIM / 32, FFN / 32, NEXP), dim3(32, 8), 0, stream>>>(W2, w2t, FFN, DIM);
    gating_kernel<<<N_TOK / 4, 256, 0, stream>>>(x, Wg, topk_e, topk_w, counts);
    prefix_kernel<<<1, 64, 0, stream>>>(counts, offs);
    scatter_kernel<<<N_TOK / 256, 256, 0, stream>>>(topk_e, topk_w, offs, cursors, entry_token, entry_wgt);
    gemm1_kernel<<<dim3(FFN / 128, 64, NEXP), 256, 0, stream>>>(xb, w1t, b1, offs, entry_token, h);
    gemm2_kernel<<<dim3(DIM / 128, 64, NEXP), 256, 0, stream>>>(h, w2t, b2, offs, entry_token, entry_wgt, y);
}